// Round 1
// baseline (59.065 us; speedup 1.0000x reference)
//
#include <hip/hip_runtime.h>
#include <math.h>

// 4-qubit circuit, one thread per batch sample. State = 16 complex amps in
// registers. Wire q <-> bit (3-q) of flat index (idx = b0*8+b1*4+b2*2+b3).

__global__ __launch_bounds__(256) void quanv_kernel(
    const float* __restrict__ x,   // [B,4]
    const float* __restrict__ w,   // [4]
    float* __restrict__ out,       // [B,4]
    int B)
{
    int b = blockIdx.x * blockDim.x + threadIdx.x;
    if (b >= B) return;

    float4 xv = reinterpret_cast<const float4*>(x)[b];

    // Embedding angles: RY(pi*x_q), gate uses t/2 -> (pi/2)*x_q
    const float HALF_PI = 1.57079632679489662f;
    float c0, s0, c1, s1, c2, s2, c3, s3;
    __sincosf(xv.x * HALF_PI, &s0, &c0);
    __sincosf(xv.y * HALF_PI, &s1, &c1);
    __sincosf(xv.z * HALF_PI, &s2, &c2);
    __sincosf(xv.w * HALF_PI, &s3, &c3);

    // Circuit weights (uniform across threads; L2/L1-cached scalar-ish loads)
    float cw0, sw0, cw1, sw1, cw2, sw2, cw3, sw3;
    __sincosf(w[0] * 0.5f, &sw0, &cw0);
    __sincosf(w[1] * 0.5f, &sw1, &cw1);
    __sincosf(w[2] * 0.5f, &sw2, &cw2);
    __sincosf(w[3] * 0.5f, &sw3, &cw3);

    // Product state after RY embedding (all real)
    float f0[2] = {c0, s0}, f1[2] = {c1, s1}, f2[2] = {c2, s2}, f3[2] = {c3, s3};
    float re[16], im[16];
#pragma unroll
    for (int i = 0; i < 16; ++i) {
        re[i] = f0[(i >> 3) & 1] * f1[(i >> 2) & 1] * f2[(i >> 1) & 1] * f3[i & 1];
        im[i] = 0.0f;
    }

    // RX(w0) on wire 0 (stride 8): [[c, -i s], [-i s, c]]
#pragma unroll
    for (int i = 0; i < 8; ++i) {
        int i0 = i, i1 = i | 8;
        float r0 = re[i0], m0 = im[i0], r1 = re[i1], m1 = im[i1];
        re[i0] = cw0 * r0 + sw0 * m1;  im[i0] = cw0 * m0 - sw0 * r1;
        re[i1] = sw0 * m0 + cw0 * r1;  im[i1] = -sw0 * r0 + cw0 * m1;
    }
    // RX(w1) on wire 1 (stride 4)
#pragma unroll
    for (int i = 0; i < 16; ++i) {
        if (i & 4) continue;
        int i0 = i, i1 = i | 4;
        float r0 = re[i0], m0 = im[i0], r1 = re[i1], m1 = im[i1];
        re[i0] = cw1 * r0 + sw1 * m1;  im[i0] = cw1 * m0 - sw1 * r1;
        re[i1] = sw1 * m0 + cw1 * r1;  im[i1] = -sw1 * r0 + cw1 * m1;
    }

    // CNOT(c=2, t=3): control bit 2 (mask 2), target mask 1
#pragma unroll
    for (int i = 0; i < 16; ++i) {
        if ((i & 2) && !(i & 1)) {
            float tr = re[i], tm = im[i];
            re[i] = re[i | 1]; im[i] = im[i | 1];
            re[i | 1] = tr;    im[i | 1] = tm;
        }
    }
    // CNOT(c=0, t=2): control mask 8, target mask 2
#pragma unroll
    for (int i = 0; i < 16; ++i) {
        if ((i & 8) && !(i & 2)) {
            float tr = re[i], tm = im[i];
            re[i] = re[i | 2]; im[i] = im[i | 2];
            re[i | 2] = tr;    im[i | 2] = tm;
        }
    }
    // CNOT(c=0, t=3): control mask 8, target mask 1
#pragma unroll
    for (int i = 0; i < 16; ++i) {
        if ((i & 8) && !(i & 1)) {
            float tr = re[i], tm = im[i];
            re[i] = re[i | 1]; im[i] = im[i | 1];
            re[i | 1] = tr;    im[i | 1] = tm;
        }
    }

    // RY(w2) on wire 0 (stride 8): [[c, -s], [s, c]] (real)
#pragma unroll
    for (int i = 0; i < 8; ++i) {
        int i0 = i, i1 = i | 8;
        float r0 = re[i0], m0 = im[i0], r1 = re[i1], m1 = im[i1];
        re[i0] = cw2 * r0 - sw2 * r1;  im[i0] = cw2 * m0 - sw2 * m1;
        re[i1] = sw2 * r0 + cw2 * r1;  im[i1] = sw2 * m0 + cw2 * m1;
    }
    // RY(w3) on wire 3 (stride 1)
#pragma unroll
    for (int i = 0; i < 16; ++i) {
        if (i & 1) continue;
        int i0 = i, i1 = i | 1;
        float r0 = re[i0], m0 = im[i0], r1 = re[i1], m1 = im[i1];
        re[i0] = cw3 * r0 - sw3 * r1;  im[i0] = cw3 * m0 - sw3 * m1;
        re[i1] = sw3 * r0 + cw3 * r1;  im[i1] = sw3 * m0 + cw3 * m1;
    }

    // <Z_q> = sum_{bit_q=0} p - sum_{bit_q=1} p
    float ev0 = 0.f, ev1 = 0.f, ev2 = 0.f, ev3 = 0.f;
#pragma unroll
    for (int i = 0; i < 16; ++i) {
        float p = re[i] * re[i] + im[i] * im[i];
        ev0 += (i & 8) ? -p : p;
        ev1 += (i & 4) ? -p : p;
        ev2 += (i & 2) ? -p : p;
        ev3 += (i & 1) ? -p : p;
    }

    reinterpret_cast<float4*>(out)[b] = make_float4(ev0, ev1, ev2, ev3);
}

extern "C" void kernel_launch(void* const* d_in, const int* in_sizes, int n_in,
                              void* d_out, int out_size, void* d_ws, size_t ws_size,
                              hipStream_t stream) {
    const float* x = (const float*)d_in[0];   // [B,4] float32
    const float* w = (const float*)d_in[1];   // [4] float32
    float* out = (float*)d_out;               // [B,4] float32
    int B = in_sizes[0] / 4;
    int block = 256;
    int grid = (B + block - 1) / block;
    quanv_kernel<<<grid, block, 0, stream>>>(x, w, out, B);
}

// Round 2
// 57.797 us; speedup vs baseline: 1.0219x; 1.0219x over previous
//
#include <hip/hip_runtime.h>
#include <math.h>

// 4-qubit circuit, one thread per sample — factored-state formulation.
//
// After AngleEmbedding the state is f0⊗f1⊗f2⊗f3 (all real). RX(w0)/RX(w1)
// keep it factored: a⊗b⊗f2⊗f3 with a,b complex 2-vectors. The CNOT chain
// (2→3, 0→2, 0→3) is a pure index permutation: h[i0][i2][i3] with
// h0 = g, h1[i2][i3] = g[1-i2][1-i3], where g[i2][i3] = f2[i2]*f3[i3^i2].
// Wire 1 stays factored to the end: <Z1> = (|b0|^2-|b1|^2) * S.
// RY(w2) mixes i0, RY(w3) mixes i3 on the 8-complex tensor C.

__global__ __launch_bounds__(256) void quanv_kernel(
    const float* __restrict__ x,   // [B,4]
    const float* __restrict__ w,   // [4]
    float* __restrict__ out,       // [B,4]
    int B)
{
    int b = blockIdx.x * blockDim.x + threadIdx.x;
    if (b >= B) return;

    float4 xv = reinterpret_cast<const float4*>(x)[b];

    const float HALF_PI = 1.57079632679489662f;
    float c0, s0, c1, s1, c2, s2, c3, s3;
    __sincosf(xv.x * HALF_PI, &s0, &c0);
    __sincosf(xv.y * HALF_PI, &s1, &c1);
    __sincosf(xv.z * HALF_PI, &s2, &c2);
    __sincosf(xv.w * HALF_PI, &s3, &c3);

    // Weight half-angle sincos (uniform across threads)
    float cw0, sw0, cw1, sw1, cw2, sw2, cw3, sw3;
    __sincosf(w[0] * 0.5f, &sw0, &cw0);
    __sincosf(w[1] * 0.5f, &sw1, &cw1);
    __sincosf(w[2] * 0.5f, &sw2, &cw2);
    __sincosf(w[3] * 0.5f, &sw3, &cw3);

    // a = RX(w0)·f0, b = RX(w1)·f1   (RX = [[c, -is],[-is, c]])
    float a0r = cw0 * c0, a0i = -sw0 * s0;
    float a1r = cw0 * s0, a1i = -sw0 * c0;
    float b0r = cw1 * c1, b0i = -sw1 * s1;
    float b1r = cw1 * s1, b1i = -sw1 * c1;
    float pb0 = b0r * b0r + b0i * b0i;
    float pb1 = b1r * b1r + b1i * b1i;

    // g[i2][i3] = f2[i2] * f3[i3 ^ i2]  (after CNOT(2,3)), k = i2*2 + i3
    float g00 = c2 * c3, g01 = c2 * s3, g10 = s2 * s3, g11 = s2 * c3;
    // h0[k] = g[k]; h1[i2][i3] = g[1-i2][1-i3]
    // u = a0 * h0, v = a1 * h1 (complex × real)
    float ur[4] = {a0r * g00, a0r * g01, a0r * g10, a0r * g11};
    float ui[4] = {a0i * g00, a0i * g01, a0i * g10, a0i * g11};
    float vr[4] = {a1r * g11, a1r * g10, a1r * g01, a1r * g00};
    float vi[4] = {a1i * g11, a1i * g10, a1i * g01, a1i * g00};

    // RY(w2) mixes i0:  A0 = cw2*u - sw2*v ; A1 = sw2*u + cw2*v
    float A0r[4], A0i[4], A1r[4], A1i[4];
#pragma unroll
    for (int k = 0; k < 4; ++k) {
        A0r[k] = cw2 * ur[k] - sw2 * vr[k];
        A0i[k] = cw2 * ui[k] - sw2 * vi[k];
        A1r[k] = sw2 * ur[k] + cw2 * vr[k];
        A1i[k] = sw2 * ui[k] + cw2 * vi[k];
    }

    // RY(w3) mixes i3 (k pairs (0,1) and (2,3)); then q = |C|^2
    float q[2][4];  // q[i0][k]
#pragma unroll
    for (int i2 = 0; i2 < 2; ++i2) {
        int k0 = i2 * 2, k1 = k0 + 1;
        float C0r = cw3 * A0r[k0] - sw3 * A0r[k1];
        float C0i = cw3 * A0i[k0] - sw3 * A0i[k1];
        float C1r = sw3 * A0r[k0] + cw3 * A0r[k1];
        float C1i = sw3 * A0i[k0] + cw3 * A0i[k1];
        q[0][k0] = C0r * C0r + C0i * C0i;
        q[0][k1] = C1r * C1r + C1i * C1i;
        float D0r = cw3 * A1r[k0] - sw3 * A1r[k1];
        float D0i = cw3 * A1i[k0] - sw3 * A1i[k1];
        float D1r = sw3 * A1r[k0] + cw3 * A1r[k1];
        float D1i = sw3 * A1i[k0] + cw3 * A1i[k1];
        q[1][k0] = D0r * D0r + D0i * D0i;
        q[1][k1] = D1r * D1r + D1i * D1i;
    }

    float s_i0_0 = q[0][0] + q[0][1] + q[0][2] + q[0][3];
    float s_i0_1 = q[1][0] + q[1][1] + q[1][2] + q[1][3];
    float S = s_i0_0 + s_i0_1;
    float z2 = (q[0][0] + q[0][1] + q[1][0] + q[1][1])
             - (q[0][2] + q[0][3] + q[1][2] + q[1][3]);
    float z3 = (q[0][0] + q[0][2] + q[1][0] + q[1][2])
             - (q[0][1] + q[0][3] + q[1][1] + q[1][3]);
    float pb_sum = pb0 + pb1;

    float ev0 = (s_i0_0 - s_i0_1) * pb_sum;
    float ev1 = (pb0 - pb1) * S;
    float ev2 = z2 * pb_sum;
    float ev3 = z3 * pb_sum;

    reinterpret_cast<float4*>(out)[b] = make_float4(ev0, ev1, ev2, ev3);
}

extern "C" void kernel_launch(void* const* d_in, const int* in_sizes, int n_in,
                              void* d_out, int out_size, void* d_ws, size_t ws_size,
                              hipStream_t stream) {
    const float* x = (const float*)d_in[0];   // [B,4] float32
    const float* w = (const float*)d_in[1];   // [4] float32
    float* out = (float*)d_out;               // [B,4] float32
    int B = in_sizes[0] / 4;
    int block = 256;
    int grid = (B + block - 1) / block;
    quanv_kernel<<<grid, block, 0, stream>>>(x, w, out, B);
}